// Round 1
// 1344.509 us; speedup vs baseline: 1.2275x; 1.2275x over previous
//
#include <hip/hip_runtime.h>

#define NB 16
#define NPTS 4096
#define NS 1024
#define NK 32
#define NCF 64

// All I/O is float32. Zero workspace bytes used. kNN parks its 32 indices
// (bit-cast to float) in the first 128B of each query's 512B output row;
// mlp_kernel reads them back and fully overwrites the row. Row ORDER of the
// 32 neighbors is irrelevant (max-pool) — only the index SET must be exact.
//
// REGISTER DISCIPLINE (r7-r11):
//  - __launch_bounds__ only CAPS VGPRs; arrays whose init source is LDS get
//    REMATERIALIZED from LDS regardless of budget (r9: (256,2) stayed VGPR 68).
//    Fix: source per-lane arrays from GLOBAL; keep the LDS copy written by
//    OTHER threads (cross-thread dataflow blocks the remat proof).
//  - R12: knn rewritten as value-only med3 scan + threshold-recovery pass.
//    The old (d2,idx) 32-deep insert paid ~210 insts EVERY iteration (wave-
//    union of per-lane triggers ~= 1) and needed 64 list VGPRs (spill-prone).
//    New scan body: 31 v_med3_f32 + 1 v_min, branch-free, ~50 VGPR total.

#define F_INF __int_as_float(0x7f800000)

#define DPP_SHR1   0x111
#define DPP_SHR2   0x112
#define DPP_SHR4   0x114
#define DPP_SHR8   0x118
#define DPP_BCAST15 0x142
#define DPP_BCAST31 0x143

// one max step of a wave64 u64-key reduction via DPP (invalid lanes keep self)
#define DPP_MAX_STEP(cur, CTRL) do{ \
  int lo_=__builtin_amdgcn_update_dpp((int)(unsigned)(cur),(int)(unsigned)(cur),CTRL,0xF,0xF,false); \
  int hi_=__builtin_amdgcn_update_dpp((int)(unsigned)((cur)>>32),(int)(unsigned)((cur)>>32),CTRL,0xF,0xF,false); \
  unsigned long long nk_=(((unsigned long long)(unsigned)hi_)<<32)|(unsigned)lo_; \
  if (nk_>(cur)) (cur)=nk_; \
}while(0)

// ---------------- FPS: 1 block/batch, 256 thr (4 waves), DPP argmax ------
// key = (dist_bits<<32) | (4095-idx): u64 max == max dist, first index.
// Point arrays sourced from GLOBAL (strided p=r*256+tid) so they stay in
// registers; LDS holds a copy only for centroid lookup + output gather.
__global__ __launch_bounds__(256, 2) void fps_kernel(
  const float* __restrict__ xyz, float* __restrict__ out)
{
  __shared__ float sxyz[NPTS*3];
  __shared__ unsigned long long skey[2][4];
  __shared__ int sfps[NS];
  const int b = blockIdx.x, tid = threadIdx.x;
  const float* bp = xyz + (size_t)b*NPTS*3;

  { // stage xyz -> LDS (cross-thread layout: blocks remat of reg arrays)
    const float4* src=(const float4*)bp;
    float4* dst=(float4*)sxyz;
    for (int i=tid;i<NPTS*3/4;i+=256) dst[i]=src[i];
  }
  // 16 points per thread in registers, FROM GLOBAL, strided p=r*256+tid
  // (p ascends with r => strict > keeps the first/smallest global index)
  float px[16],py[16],pz[16],dist[16];
  #pragma unroll
  for (int r=0;r<16;r++){
    int p=r*256+tid;
    px[r]=bp[p*3]; py[r]=bp[p*3+1]; pz[r]=bp[p*3+2];
    dist[r]=1e10f;
  }
  __syncthreads();
  int far=0;
  for (int s=0;s<NS;++s){
    float cx=sxyz[far*3],cy=sxyz[far*3+1],cz=sxyz[far*3+2];
    float bv=-1.0f; int bslot=0;
    #pragma unroll
    for (int r=0;r<16;r++){
      float dx=__fsub_rn(px[r],cx);
      float dy=__fsub_rn(py[r],cy);
      float dz=__fsub_rn(pz[r],cz);
      float d2=__fadd_rn(__fadd_rn(__fmul_rn(dx,dx),__fmul_rn(dy,dy)),__fmul_rn(dz,dz));
      float nd=fminf(dist[r],d2);
      dist[r]=nd;
      if (nd>bv){bv=nd;bslot=r;}      // strict > keeps first index in lane
    }
    int bidx=bslot*256+tid;
    unsigned long long cur=(((unsigned long long)__float_as_uint(bv))<<32)
                           |(unsigned)(4095-bidx);
    DPP_MAX_STEP(cur,DPP_SHR1);
    DPP_MAX_STEP(cur,DPP_SHR2);
    DPP_MAX_STEP(cur,DPP_SHR4);
    DPP_MAX_STEP(cur,DPP_SHR8);
    DPP_MAX_STEP(cur,DPP_BCAST15);
    DPP_MAX_STEP(cur,DPP_BCAST31);
    const int par=s&1;
    if ((tid&63)==63) skey[par][tid>>6]=cur;
    __syncthreads();
    unsigned long long m=skey[par][0];
    #pragma unroll
    for (int w=1;w<4;w++){ unsigned long long o=skey[par][w]; if (o>m) m=o; }
    far=4095-(int)(m&0xFFFFFFFFu);
    if (tid==0) sfps[s]=far;
  }
  __syncthreads();
  for (int s=tid;s<NS;s+=256){
    int p=sfps[s];
    size_t o=((size_t)b*NS+s)*3;
    out[o]=sxyz[p*3]; out[o+1]=sxyz[p*3+1]; out[o+2]=sxyz[p*3+2];
  }
}

// ---------------- kNN: 256 thr (4 waves), 16 queries/block ----------------
// 16 lanes/query scan interleaved 256-pt partitions from GLOBAL (L1/L2).
// Pass A: branch-free VALUE-ONLY sorted top-32 per lane (31 med3 + 1 min per
//   point; non-inserting d2 is a provable no-op on a sorted list).
// Merge: single dump (stride-33, conflict-free), 4->1 then 4->1 value merge
//   per query -> Tq = exact 32nd-smallest d2 + multiplicity e of Tq in top-32.
// Pass B: rescan with bit-identical d2; d2<Tq -> atomic-append index (order
//   irrelevant by contract), d2==Tq -> tie buffer; e smallest tie indices
//   complete the set (== lax.top_k stability). Exact index SET, any order.
__global__ __launch_bounds__(256, 4) void knn_kernel(
  const float* __restrict__ xyz, const float* __restrict__ newxyz,
  float* __restrict__ out2)
{
  __shared__ float sdump[256*33];   // 33.0 KB, per-lane sorted values
  __shared__ float sl1[64*33];      // 8.25 KB, level-1 merged values
  __shared__ float sTq[16];
  __shared__ int   sE[16];
  __shared__ int   sCnt[16];
  __shared__ int   sTCnt[16];
  __shared__ int   sIdx[16][32];
  __shared__ int   sTie[16][48];
  const int tid=threadIdx.x;
  const int wave=tid>>6, lane=tid&63;
  const int qw=lane>>4;               // query-within-wave 0..3
  const int part=lane&15;             // partition 0..15
  const int ql=wave*4+qw;             // query-within-block 0..15
  const int gq=blockIdx.x*16+ql;
  const int b=gq>>10;
  const float* base=xyz+(size_t)b*NPTS*3;

  float ax=newxyz[(size_t)gq*3],ay=newxyz[(size_t)gq*3+1],az=newxyz[(size_t)gq*3+2];
  float a2=__fadd_rn(__fadd_rn(__fmul_rn(ax,ax),__fmul_rn(ay,ay)),__fmul_rn(az,az));

  float kD[NK];
  #pragma unroll
  for (int p=0;p<NK;p++) kD[p]=F_INF;

  #pragma unroll 2
  for (int t=0;t<NPTS/16;++t){
    int n=(t<<4)|part;
    float bx=base[n*3],by=base[n*3+1],bz=base[n*3+2];
    float b2=__fadd_rn(__fadd_rn(__fmul_rn(bx,bx),__fmul_rn(by,by)),__fmul_rn(bz,bz));
    float ab=__fadd_rn(__fadd_rn(__fmul_rn(ax,bx),__fmul_rn(ay,by)),__fmul_rn(az,bz));
    float tt=__fadd_rn(__fsub_rn(a2,__fmul_rn(2.0f,ab)),b2);
    float d2=fmaxf(tt,0.0f);
    // branch-free sorted insert (values only). Descending p reads kD[p-1]
    // before it is rewritten; if d2 >= kD[31] every med3 is an identity.
    #pragma unroll
    for (int p=NK-1;p>0;--p)
      kD[p]=__builtin_amdgcn_fmed3f(kD[p-1],d2,kD[p]);
    kD[0]=fminf(kD[0],d2);
  }

  // dump per-lane sorted values (stride 33 => lane-conflict-free b32 writes)
  #pragma unroll
  for (int p=0;p<NK;p++) sdump[tid*33+p]=kD[p];
  __syncthreads();

  // level 1: 64 threads, each merges 4 lane-lists of one query
  if (tid<64){
    int qq=tid>>2, g=tid&3;
    int rbase=(qq>>2)*64+(qq&3)*16+g*4;   // tid of first contributing lane
    const float* r0=sdump+(size_t)(rbase+0)*33;
    const float* r1=sdump+(size_t)(rbase+1)*33;
    const float* r2=sdump+(size_t)(rbase+2)*33;
    const float* r3=sdump+(size_t)(rbase+3)*33;
    float* o=sl1+(size_t)tid*33;
    int h0=0,h1=0,h2=0,h3=0;
    float c0=r0[0],c1=r1[0],c2=r2[0],c3=r3[0];
    #pragma unroll 1
    for (int i=0;i<NK;++i){
      bool s01=c1<c0; float m01=s01?c1:c0;
      bool s23=c3<c2; float m23=s23?c3:c2;
      bool sm=m23<m01; float m=sm?m23:m01;
      o[i]=m;
      int w=sm?(s23?3:2):(s01?1:0);
      if (w==0){h0++; c0=(h0<NK)?r0[h0]:F_INF;}
      else if (w==1){h1++; c1=(h1<NK)?r1[h1]:F_INF;}
      else if (w==2){h2++; c2=(h2<NK)?r2[h2]:F_INF;}
      else {h3++; c3=(h3<NK)?r3[h3]:F_INF;}
    }
  }
  __syncthreads();

  // level 2: 16 threads -> Tq (32nd smallest) + multiplicity e within top-32
  if (tid<16){
    const float* r0=sl1+(size_t)(tid*4+0)*33;
    const float* r1=sl1+(size_t)(tid*4+1)*33;
    const float* r2=sl1+(size_t)(tid*4+2)*33;
    const float* r3=sl1+(size_t)(tid*4+3)*33;
    int h0=0,h1=0,h2=0,h3=0;
    float c0=r0[0],c1=r1[0],c2=r2[0],c3=r3[0];
    float prev=-1.0f; int run=0;
    #pragma unroll 1
    for (int i=0;i<NK;++i){
      bool s01=c1<c0; float m01=s01?c1:c0;
      bool s23=c3<c2; float m23=s23?c3:c2;
      bool sm=m23<m01; float m=sm?m23:m01;
      if (m==prev) run++; else {prev=m; run=1;}
      int w=sm?(s23?3:2):(s01?1:0);
      if (w==0){h0++; c0=(h0<NK)?r0[h0]:F_INF;}
      else if (w==1){h1++; c1=(h1<NK)?r1[h1]:F_INF;}
      else if (w==2){h2++; c2=(h2<NK)?r2[h2]:F_INF;}
      else {h3++; c3=(h3<NK)?r3[h3]:F_INF;}
    }
    sTq[tid]=prev; sE[tid]=run;
    sCnt[tid]=0; sTCnt[tid]=0;
  }
  __syncthreads();

  // pass B: recovery rescan with bit-identical arithmetic
  {
    const float Tq=sTq[ql];
    #pragma unroll 2
    for (int t=0;t<NPTS/16;++t){
      int n=(t<<4)|part;
      float bx=base[n*3],by=base[n*3+1],bz=base[n*3+2];
      float b2=__fadd_rn(__fadd_rn(__fmul_rn(bx,bx),__fmul_rn(by,by)),__fmul_rn(bz,bz));
      float ab=__fadd_rn(__fadd_rn(__fmul_rn(ax,bx),__fmul_rn(ay,by)),__fmul_rn(az,bz));
      float tt=__fadd_rn(__fsub_rn(a2,__fmul_rn(2.0f,ab)),b2);
      float d2=fmaxf(tt,0.0f);
      if (d2<Tq){
        int pos=atomicAdd(&sCnt[ql],1);
        if (pos<32) sIdx[ql][pos]=n;        // pos<=30 guaranteed (c<=31)
      } else if (d2==Tq){
        int tp=atomicAdd(&sTCnt[ql],1);
        if (tp<48) sTie[ql][tp]=n;          // >=e entries always land here
      }
    }
  }
  __syncthreads();

  // finalize: append the e smallest tie indices (== top_k stable tie-break)
  if (tid<16){
    int e=sE[tid], c=sCnt[tid];
    int tn=sTCnt[tid]; if (tn>48) tn=48;
    for (int j=0;j<e;++j){
      int bm=0x7FFFFFFF, bi=0;
      for (int i=0;i<tn;++i){ int v=sTie[tid][i]; if (v<bm){bm=v;bi=i;} }
      sTie[tid][bi]=0x7FFFFFFF;
      if (c+j<32) sIdx[tid][c+j]=bm;
    }
  }
  __syncthreads();

  for (int i=tid;i<512;i+=256){
    int q=i>>5, k=i&31;
    out2[(size_t)(blockIdx.x*16+q)*128+k]=__int_as_float(sIdx[q][k]);
  }
}

// ---------------- fused group + MLP(3) + maxpool --------------------------
// 128 threads = 4 queries x 32 neighbor rows. float4 weight loads.
__global__ __launch_bounds__(128, 3) void mlp_kernel(
  const float* __restrict__ feat, const float* __restrict__ xyz,
  const float* __restrict__ newxyz,
  const float* __restrict__ W0,const float* __restrict__ b0,
  const float* __restrict__ g0,const float* __restrict__ be0,
  const float* __restrict__ m0,const float* __restrict__ v0,
  const float* __restrict__ W1,const float* __restrict__ b1,
  const float* __restrict__ g1,const float* __restrict__ be1,
  const float* __restrict__ m1,const float* __restrict__ v1,
  const float* __restrict__ W2,const float* __restrict__ b2,
  const float* __restrict__ g2,const float* __restrict__ be2,
  const float* __restrict__ m2,const float* __restrict__ v2,
  float* __restrict__ out2)
{
  __shared__ float sX[128*67];
  const int tid=threadIdx.x;
  const int q=blockIdx.x*4+(tid>>5);
  const int k=tid&31;
  const int b=q>>10;
  const int pt=__float_as_int(out2[(size_t)q*128+k]);

  float* myx=sX+tid*67;
  {
    const float* nx=newxyz+(size_t)q*3;
    const float* pp=xyz+((size_t)b*NPTS+pt)*3;
    myx[0]=pp[0]-nx[0]; myx[1]=pp[1]-nx[1]; myx[2]=pp[2]-nx[2];
    const float4* fp=(const float4*)(feat+((size_t)b*NPTS+pt)*NCF);
    #pragma unroll
    for (int i=0;i<16;i++){
      float4 u=fp[i]; float* d=myx+3+i*4;
      d[0]=u.x; d[1]=u.y; d[2]=u.z; d[3]=u.w;
    }
  }
  float acc[64];
  // layer 1: 67 -> 64
  #pragma unroll
  for (int c=0;c<64;c++) acc[c]=b0[c];
  #pragma unroll 2
  for (int j=0;j<67;++j){
    float xj=myx[j];
    const float4* wr=(const float4*)(W0+j*64);
    #pragma unroll
    for (int c4=0;c4<16;c4++){
      float4 w=wr[c4];
      acc[c4*4+0]=fmaf(xj,w.x,acc[c4*4+0]);
      acc[c4*4+1]=fmaf(xj,w.y,acc[c4*4+1]);
      acc[c4*4+2]=fmaf(xj,w.z,acc[c4*4+2]);
      acc[c4*4+3]=fmaf(xj,w.w,acc[c4*4+3]);
    }
  }
  #pragma unroll
  for (int c=0;c<64;c++){
    float A=g0[c]*rsqrtf(v0[c]+1e-3f);
    myx[c]=fmaf(A,fmaxf(acc[c],0.0f),be0[c]-m0[c]*A);
  }
  // layer 2: 64 -> 64
  #pragma unroll
  for (int c=0;c<64;c++) acc[c]=b1[c];
  #pragma unroll 2
  for (int j=0;j<64;++j){
    float xj=myx[j];
    const float4* wr=(const float4*)(W1+j*64);
    #pragma unroll
    for (int c4=0;c4<16;c4++){
      float4 w=wr[c4];
      acc[c4*4+0]=fmaf(xj,w.x,acc[c4*4+0]);
      acc[c4*4+1]=fmaf(xj,w.y,acc[c4*4+1]);
      acc[c4*4+2]=fmaf(xj,w.z,acc[c4*4+2]);
      acc[c4*4+3]=fmaf(xj,w.w,acc[c4*4+3]);
    }
  }
  #pragma unroll
  for (int c=0;c<64;c++){
    float A=g1[c]*rsqrtf(v1[c]+1e-3f);
    myx[c]=fmaf(A,fmaxf(acc[c],0.0f),be1[c]-m1[c]*A);
  }
  // layer 3: 64 -> 128, two 64-col chunks (keeps VGPR low)
  #pragma unroll 1
  for (int ch=0;ch<2;++ch){
    const int co=ch*64;
    #pragma unroll
    for (int c=0;c<64;c++) acc[c]=b2[co+c];
    #pragma unroll 2
    for (int j=0;j<64;++j){
      float xj=myx[j];
      const float4* wr=(const float4*)(W2+j*128+co);
      #pragma unroll
      for (int c4=0;c4<16;c4++){
        float4 w=wr[c4];
        acc[c4*4+0]=fmaf(xj,w.x,acc[c4*4+0]);
        acc[c4*4+1]=fmaf(xj,w.y,acc[c4*4+1]);
        acc[c4*4+2]=fmaf(xj,w.z,acc[c4*4+2]);
        acc[c4*4+3]=fmaf(xj,w.w,acc[c4*4+3]);
      }
    }
    #pragma unroll
    for (int c=0;c<64;c++){
      float A=g2[co+c]*rsqrtf(v2[co+c]+1e-3f);
      float v=fmaf(A,fmaxf(acc[c],0.0f),be2[co+c]-m2[co+c]*A);
      v=fmaxf(v,__shfl_xor(v,1));
      v=fmaxf(v,__shfl_xor(v,2));
      v=fmaxf(v,__shfl_xor(v,4));
      v=fmaxf(v,__shfl_xor(v,8));
      v=fmaxf(v,__shfl_xor(v,16));
      acc[c]=v;
    }
    if (k==0){
      float4* op=(float4*)(out2+(size_t)q*128+co);
      #pragma unroll
      for (int c=0;c<64;c+=4)
        op[c/4]=make_float4(acc[c],acc[c+1],acc[c+2],acc[c+3]);
    }
  }
}

extern "C" void kernel_launch(void* const* d_in, const int* in_sizes, int n_in,
                              void* d_out, int out_size, void* d_ws, size_t ws_size,
                              hipStream_t stream)
{
  const float* xyz=(const float*)d_in[0];
  const float* feat=(const float*)d_in[1];
  float* out=(float*)d_out;
  float* out2=out+(size_t)NB*NS*3;     // pooled-feature region
  (void)d_ws; (void)ws_size;

  fps_kernel<<<NB,256,0,stream>>>(xyz,out);
  knn_kernel<<<NB*NS/16,256,0,stream>>>(xyz,out,out2);
  mlp_kernel<<<NB*NS/4,128,0,stream>>>(feat,xyz,out,
    (const float*)d_in[2],(const float*)d_in[3],
    (const float*)d_in[4],(const float*)d_in[5],
    (const float*)d_in[6],(const float*)d_in[7],
    (const float*)d_in[8],(const float*)d_in[9],
    (const float*)d_in[10],(const float*)d_in[11],
    (const float*)d_in[12],(const float*)d_in[13],
    (const float*)d_in[14],(const float*)d_in[15],
    (const float*)d_in[16],(const float*)d_in[17],
    (const float*)d_in[18],(const float*)d_in[19],
    out2);
}